// Round 1
// baseline (1687.562 us; speedup 1.0000x reference)
//
#include <hip/hip_runtime.h>
#include <math.h>

#define B_    32768
#define LN10_ 2.302585092994046f

typedef __attribute__((ext_vector_type(8))) short short8;
typedef __attribute__((ext_vector_type(4))) float f32x4;

typedef const __attribute__((address_space(1))) void gvoid_t;
typedef __attribute__((address_space(3))) void svoid_t;

__device__ __forceinline__ void gl16(const void* g, void* l) {
  __builtin_amdgcn_global_load_lds((gvoid_t*)g, (svoid_t*)l, 16, 0, 0);
}

__device__ __forceinline__ float bf2f(unsigned int u) {
  union { unsigned int i; float f; } v; v.i = u << 16; return v.f;
}
// round-to-nearest-even f32 -> bf16 (finite inputs)
__device__ __forceinline__ unsigned short f2bf(float f) {
  union { float f; unsigned int i; } v; v.f = f;
  unsigned int x = v.i;
  unsigned int r = x + 0x7FFFu + ((x >> 16) & 1u);
  return (unsigned short)(r >> 16);
}

// ---------------- GEMM: C[m,n] = sum_k A[m,k] * W[n,k]  (+bias, +elu), bf16 in/out, fp32 acc
// grid: (N/128, M/128), block 256. Tile 128x128x64, m97 structure.
__global__ __launch_bounds__(256)
void gemm_bt(const unsigned short* __restrict__ A, int lda,
             const unsigned short* __restrict__ W, int ldw,
             unsigned short* __restrict__ C, int ldc,
             int K, const float* __restrict__ bias, int elu) {
  __shared__ __align__(16) unsigned short lA[128 * 64];
  __shared__ __align__(16) unsigned short lB[128 * 64];
  const int t = threadIdx.x;
  const int mBase = blockIdx.y * 128;
  const int nBase = blockIdx.x * 128;
  const unsigned short* Ap = A + (size_t)mBase * lda;
  const unsigned short* Wp = W + (size_t)nBase * ldw;
  const int w = t >> 6, l = t & 63;
  const int wr = (w >> 1) * 64, wc = (w & 1) * 64;
  const int lm = l & 15, lg = l >> 4;

  f32x4 acc[4][4];
#pragma unroll
  for (int i = 0; i < 4; ++i)
#pragma unroll
    for (int j = 0; j < 4; ++j) {
      f32x4 z4 = {0.f, 0.f, 0.f, 0.f};
      acc[i][j] = z4;
    }

  for (int k0 = 0; k0 < K; k0 += 64) {
    __syncthreads();
#pragma unroll
    for (int it = 0; it < 4; ++it) {
      int chunk = it * 256 + t;
      int row = chunk >> 3, c8 = (chunk & 7) << 3;
      gl16(Ap + (size_t)row * lda + k0 + c8, &lA[chunk * 8]);
      gl16(Wp + (size_t)row * ldw + k0 + c8, &lB[chunk * 8]);
    }
    __syncthreads();
#pragma unroll
    for (int kk = 0; kk < 64; kk += 32) {
      short8 af[4], bfr[4];
#pragma unroll
      for (int i = 0; i < 4; ++i)
        af[i] = *(const short8*)&lA[(wr + i * 16 + lm) * 64 + kk + lg * 8];
#pragma unroll
      for (int j = 0; j < 4; ++j)
        bfr[j] = *(const short8*)&lB[(wc + j * 16 + lm) * 64 + kk + lg * 8];
#pragma unroll
      for (int i = 0; i < 4; ++i)
#pragma unroll
        for (int j = 0; j < 4; ++j)
          acc[i][j] = __builtin_amdgcn_mfma_f32_16x16x32_bf16(af[i], bfr[j], acc[i][j], 0, 0, 0);
    }
  }

  // epilogue: D row = (lane>>4)*4 + reg, col = lane&15
#pragma unroll
  for (int j = 0; j < 4; ++j) {
    int n = nBase + wc + j * 16 + lm;
    float bj = bias ? bias[n] : 0.f;
#pragma unroll
    for (int i = 0; i < 4; ++i) {
      int m0 = mBase + wr + i * 16 + lg * 4;
#pragma unroll
      for (int r = 0; r < 4; ++r) {
        float v = acc[i][j][r] + bj;
        if (elu) v = v > 0.f ? v : expm1f(v);
        C[(size_t)(m0 + r) * ldc + n] = f2bf(v);
      }
    }
  }
}

// ---------------- column sums / sumsq over bf16 [B,N]; st[0..N)=sum, st[N..2N)=sumsq
__global__ void col_stats(const unsigned short* __restrict__ Y, float* __restrict__ st,
                          int N, int rowsPer) {
  int g = blockIdx.x * blockDim.x + threadIdx.x;
  int col = g * 4;
  size_t r0 = (size_t)blockIdx.y * rowsPer;
  float s0 = 0, s1 = 0, s2 = 0, s3 = 0, q0 = 0, q1 = 0, q2 = 0, q3 = 0;
  const unsigned short* p = Y + r0 * N + col;
  for (int r = 0; r < rowsPer; ++r) {
    ushort4 u = *(const ushort4*)p;
    float v0 = bf2f(u.x), v1 = bf2f(u.y), v2 = bf2f(u.z), v3 = bf2f(u.w);
    s0 += v0; q0 += v0 * v0;
    s1 += v1; q1 += v1 * v1;
    s2 += v2; q2 += v2 * v2;
    s3 += v3; q3 += v3 * v3;
    p += N;
  }
  atomicAdd(&st[col + 0], s0); atomicAdd(&st[col + 1], s1);
  atomicAdd(&st[col + 2], s2); atomicAdd(&st[col + 3], s3);
  atomicAdd(&st[N + col + 0], q0); atomicAdd(&st[N + col + 1], q1);
  atomicAdd(&st[N + col + 2], q2); atomicAdd(&st[N + col + 3], q3);
}

// ---------------- fold BN to per-column a*y+b: ab[0..N)=a, ab[N..2N)=b
__global__ void bn_finalize(const float* __restrict__ st, const float* __restrict__ gam,
                            const float* __restrict__ bet, float* __restrict__ ab,
                            int N, float invB) {
  int c = blockIdx.x * blockDim.x + threadIdx.x;
  if (c < N) {
    float m = st[c] * invB;
    float v = st[N + c] * invB - m * m;
    float a = gam[c] * rsqrtf(v + 1e-5f);
    ab[c] = a;
    ab[N + c] = bet[c] - m * a;
  }
}

// ---------------- in-place BN + ELU on bf16 [B,N], 8 elems/thread
__global__ void bn_apply(unsigned short* __restrict__ Y, const float* __restrict__ ab, int N) {
  size_t i = (size_t)blockIdx.x * blockDim.x + threadIdx.x;
  size_t base = i * 8;
  int col = (int)(base % (size_t)N);
  uint4 u = *(uint4*)&Y[base];
  unsigned int uu[4] = {u.x, u.y, u.z, u.w};
  unsigned int oo[4];
#pragma unroll
  for (int k = 0; k < 4; ++k) {
    float vlo = bf2f(uu[k] & 0xFFFFu);
    float vhi = bf2f(uu[k] >> 16);
    int c = col + 2 * k;
    float flo = ab[c] * vlo + ab[N + c];
    float fhi = ab[c + 1] * vhi + ab[N + c + 1];
    flo = flo > 0.f ? flo : expm1f(flo);
    fhi = fhi > 0.f ? fhi : expm1f(fhi);
    oo[k] = (unsigned int)f2bf(flo) | ((unsigned int)f2bf(fhi) << 16);
  }
  uint4 o = {oo[0], oo[1], oo[2], oo[3]};
  *(uint4*)&Y[base] = o;
}

// ---------------- fp32 -> bf16 cast (4/thread)
__global__ void castk(const float* __restrict__ s, unsigned short* __restrict__ d, int n4) {
  int i = blockIdx.x * blockDim.x + threadIdx.x;
  if (i < n4) {
    float4 v = ((const float4*)s)[i];
    ushort4 o = {f2bf(v.x), f2bf(v.y), f2bf(v.z), f2bf(v.w)};
    ((ushort4*)d)[i] = o;
  }
}

// ---------------- cast x [B,512] fp32 into z[:,128:640] bf16 (ld 640)
__global__ void cast_x(const float* __restrict__ x, unsigned short* __restrict__ z) {
  int i = blockIdx.x * blockDim.x + threadIdx.x;  // over B*128
  int b = i >> 7;
  int c = (i & 127) << 2;
  float4 v = *(const float4*)&x[(size_t)b * 512 + c];
  ushort4 o = {f2bf(v.x), f2bf(v.y), f2bf(v.z), f2bf(v.w)};
  *(ushort4*)&z[(size_t)b * 640 + 128 + c] = o;
}

// ---------------- final: select expert, dot(t2[e,b,:], w3[e,:]) + b3[e], softplus
__global__ void final_pred(const unsigned short* __restrict__ t2, const int* __restrict__ gidx,
                           const float* __restrict__ w3, const float* __restrict__ b3,
                           float* __restrict__ out) {
  int row = blockIdx.x * 4 + (threadIdx.x >> 6);
  int l = threadIdx.x & 63;
  int e = gidx[row];
  const unsigned short* p = t2 + ((size_t)e * B_ + row) * 256 + l * 4;
  ushort4 u = *(const ushort4*)p;
  float4 wv = *(const float4*)&w3[e * 256 + l * 4];
  float sum = bf2f(u.x) * wv.x + bf2f(u.y) * wv.y + bf2f(u.z) * wv.z + bf2f(u.w) * wv.w;
#pragma unroll
  for (int off = 32; off; off >>= 1) sum += __shfl_down(sum, off, 64);
  if (l == 0) {
    float xr = sum + b3[e];
    float sp = (xr > 0.f) ? (xr + log1pf(expf(-xr))) : log1pf(expf(xr));
    float pl = -sp;
    out[row] = pl;
    out[B_ + row] = expf(pl * LN10_);
  }
}

extern "C" void kernel_launch(void* const* d_in, const int* in_sizes, int n_in,
                              void* d_out, int out_size, void* d_ws, size_t ws_size,
                              hipStream_t stream) {
  const float* x    = (const float*)d_in[0];
  const int*   gidx = (const int*)d_in[1];
  const float* e_w1 = (const float*)d_in[2];
  const float* e_g1 = (const float*)d_in[4];
  const float* e_be1= (const float*)d_in[5];
  const float* e_w2 = (const float*)d_in[6];
  const float* e_g2 = (const float*)d_in[8];
  const float* e_be2= (const float*)d_in[9];
  const float* e_w3 = (const float*)d_in[10];
  const float* e_b3 = (const float*)d_in[11];
  const float* s_w1 = (const float*)d_in[12];
  const float* s_g1 = (const float*)d_in[14];
  const float* s_be1= (const float*)d_in[15];
  const float* s_w2 = (const float*)d_in[16];
  const float* s_g2 = (const float*)d_in[18];
  const float* s_be2= (const float*)d_in[19];
  const float* h_w1 = (const float*)d_in[20];
  const float* h_b1 = (const float*)d_in[21];
  const float* h_w2 = (const float*)d_in[22];
  const float* h_b2 = (const float*)d_in[23];
  const float* h_w3 = (const float*)d_in[24];
  const float* h_b3 = (const float*)d_in[25];
  float* out = (float*)d_out;

  char* ws = (char*)d_ws;
  size_t off = 0;
  auto alloc = [&](size_t bytes) -> char* {
    char* p = ws + off;
    off += (bytes + 255) & ~(size_t)255;
    return p;
  };
  unsigned short* wb_e1 = (unsigned short*)alloc((size_t)2048 * 512 * 2);
  unsigned short* wb_e2 = (unsigned short*)alloc((size_t)1024 * 2048 * 2);
  unsigned short* wb_e3 = (unsigned short*)alloc((size_t)128 * 1024 * 2);
  unsigned short* wb_s1 = (unsigned short*)alloc((size_t)2048 * 640 * 2);
  unsigned short* wb_s2 = (unsigned short*)alloc((size_t)1024 * 2048 * 2);
  unsigned short* wb_h1 = (unsigned short*)alloc((size_t)3 * 512 * 1024 * 2);
  unsigned short* wb_h2 = (unsigned short*)alloc((size_t)3 * 256 * 512 * 2);
  unsigned short* z     = (unsigned short*)alloc((size_t)B_ * 640 * 2);
  unsigned short* bufA  = (unsigned short*)alloc((size_t)B_ * 2048 * 2);
  unsigned short* bufB  = (unsigned short*)alloc((size_t)B_ * 1024 * 2);
  float* st = (float*)alloc(2 * 2048 * sizeof(float));
  float* ab = (float*)alloc(2 * 2048 * sizeof(float));

  auto cast = [&](const float* s, unsigned short* d, size_t n) {
    int n4 = (int)(n / 4);
    castk<<<(n4 + 255) / 256, 256, 0, stream>>>(s, d, n4);
  };
  cast(e_w1, wb_e1, (size_t)2048 * 512);
  cast(e_w2, wb_e2, (size_t)1024 * 2048);
  cast(e_w3, wb_e3, (size_t)128 * 1024);
  cast(s_w1, wb_s1, (size_t)2048 * 640);
  cast(s_w2, wb_s2, (size_t)1024 * 2048);
  cast(h_w1, wb_h1, (size_t)3 * 512 * 1024);
  cast(h_w2, wb_h2, (size_t)3 * 256 * 512);
  cast_x<<<(B_ * 128) / 256, 256, 0, stream>>>(x, z);

  auto bn = [&](unsigned short* Y, int N, const float* g, const float* be) {
    hipMemsetAsync(st, 0, (size_t)2 * N * sizeof(float), stream);
    col_stats<<<dim3(N / 1024, 128), 256, 0, stream>>>(Y, st, N, B_ / 128);
    bn_finalize<<<(N + 255) / 256, 256, 0, stream>>>(st, g, be, ab, N, 1.0f / B_);
    bn_apply<<<(int)((size_t)B_ * N / 2048), 256, 0, stream>>>(Y, ab, N);
  };

  // encoder L1: [B,512] x [2048,512]^T -> bufA
  gemm_bt<<<dim3(16, 256), 256, 0, stream>>>(z + 128, 640, wb_e1, 512, bufA, 2048, 512, nullptr, 0);
  bn(bufA, 2048, e_g1, e_be1);
  // encoder L2: [B,2048] x [1024,2048]^T -> bufB
  gemm_bt<<<dim3(8, 256), 256, 0, stream>>>(bufA, 2048, wb_e2, 2048, bufB, 1024, 2048, nullptr, 0);
  bn(bufB, 1024, e_g2, e_be2);
  // latent: [B,1024] x [128,1024]^T -> z[:,0:128] (ldc 640), +e_b3
  gemm_bt<<<dim3(1, 256), 256, 0, stream>>>(bufB, 1024, wb_e3, 1024, z, 640, 1024, e_b3, 0);
  // shared L1: [B,640] x [2048,640]^T -> bufA
  gemm_bt<<<dim3(16, 256), 256, 0, stream>>>(z, 640, wb_s1, 640, bufA, 2048, 640, nullptr, 0);
  bn(bufA, 2048, s_g1, s_be1);
  // shared L2: [B,2048] x [1024,2048]^T -> bufB (= hidden)
  gemm_bt<<<dim3(8, 256), 256, 0, stream>>>(bufA, 2048, wb_s2, 2048, bufB, 1024, 2048, nullptr, 0);
  bn(bufB, 1024, s_g2, s_be2);

  // heads: t1_e = elu(hidden @ h_w1[e]^T + h_b1[e]) -> bufA slices
  for (int e = 0; e < 3; ++e)
    gemm_bt<<<dim3(4, 256), 256, 0, stream>>>(bufB, 1024, wb_h1 + (size_t)e * 512 * 1024, 1024,
                                              bufA + (size_t)e * B_ * 512, 512, 1024,
                                              h_b1 + e * 512, 1);
  // t2_e = elu(t1_e @ h_w2[e]^T + h_b2[e]) -> bufB slices (hidden dead now)
  for (int e = 0; e < 3; ++e)
    gemm_bt<<<dim3(2, 256), 256, 0, stream>>>(bufA + (size_t)e * B_ * 512, 512,
                                              wb_h2 + (size_t)e * 256 * 512, 512,
                                              bufB + (size_t)e * B_ * 256, 256, 512,
                                              h_b2 + e * 256, 1);

  final_pred<<<B_ / 4, 256, 0, stream>>>(bufB, gidx, h_w3, h_b3, out);
}

// Round 4
// 1254.546 us; speedup vs baseline: 1.3452x; 1.3452x over previous
//
#include <hip/hip_runtime.h>
#include <math.h>

#define B_    32768
#define LN10_ 2.302585092994046f

typedef __attribute__((ext_vector_type(8))) short short8;
typedef __attribute__((ext_vector_type(4))) float f32x4;

typedef const __attribute__((address_space(1))) void gvoid_t;
typedef __attribute__((address_space(3))) void svoid_t;

__device__ __forceinline__ void gl16(const void* g, void* l) {
  __builtin_amdgcn_global_load_lds((gvoid_t*)g, (svoid_t*)l, 16, 0, 0);
}

__device__ __forceinline__ float bf2f(unsigned int u) {
  union { unsigned int i; float f; } v; v.i = u << 16; return v.f;
}
// round-to-nearest-even f32 -> bf16 (finite inputs)
__device__ __forceinline__ unsigned short f2bf(float f) {
  union { float f; unsigned int i; } v; v.f = f;
  unsigned int x = v.i;
  unsigned int r = x + 0x7FFFu + ((x >> 16) & 1u);
  return (unsigned short)(r >> 16);
}

// ---------------- GEMM: C[m,n] = sum_k A[m,k] * W[n,k]  (+bias, +elu, +col-stats)
// bf16 in/out, fp32 acc. grid: (N/128, M/128, E), block 256. Tile 128x128x64.
// LDS XOR swizzle: 16B slot s of row r holds global chunk s^(r&7) (verified
// bit-exact on HW: R2 vs R3 identical outputs). Read slot = ac^(ar&7) spreads
// a wave64 ds_read_b128 across all 32 banks, 8 words/bank (balanced).
// Block swizzle: xcd = flat&7 owns a contiguous band of m-tiles, n fastest,
// so blocks sharing an A-panel are temporally adjacent on one XCD's L2.
// Batched experts via blockIdx.z with strides eA/eW/eC/eBias (eA was the R2/R3 bug).
__global__ __launch_bounds__(256)
void gemm_bt(const unsigned short* __restrict__ A0, int lda,
             const unsigned short* __restrict__ W0, int ldw,
             unsigned short* __restrict__ C0, int ldc,
             int K, const float* __restrict__ bias0, int elu,
             float* __restrict__ st, int Ntot,
             long eA, long eW, long eC, int eBias) {
  __shared__ __align__(16) unsigned short lA[128 * 64];
  __shared__ __align__(16) unsigned short lB[128 * 64];
  const int t = threadIdx.x;
  const int nx = gridDim.x, ny = gridDim.y;
  const int f = blockIdx.y * nx + blockIdx.x;
  const int xcd = f & 7, g = f >> 3;
  const int gdiv = g / nx;
  const int mt = xcd * (ny >> 3) + gdiv;
  const int nt = g - gdiv * nx;
  const int mBase = mt * 128;
  const int nBase = nt * 128;
  const unsigned short* A = A0 + (size_t)blockIdx.z * eA;
  const unsigned short* W = W0 + (size_t)blockIdx.z * eW;
  unsigned short* C = C0 + (size_t)blockIdx.z * eC;
  const float* bias = bias0 ? (bias0 + (size_t)blockIdx.z * eBias) : nullptr;
  const unsigned short* Ap = A + (size_t)mBase * lda;
  const unsigned short* Wp = W + (size_t)nBase * ldw;
  const int w = t >> 6, l = t & 63;
  const int wr = (w >> 1) * 64, wc = (w & 1) * 64;
  const int lm = l & 15, lg = l >> 4;

  f32x4 acc[4][4];
#pragma unroll
  for (int i = 0; i < 4; ++i)
#pragma unroll
    for (int j = 0; j < 4; ++j) {
      f32x4 z4 = {0.f, 0.f, 0.f, 0.f};
      acc[i][j] = z4;
    }

  for (int k0 = 0; k0 < K; k0 += 64) {
    __syncthreads();
#pragma unroll
    for (int it = 0; it < 4; ++it) {
      int chunk = it * 256 + t;
      int row = chunk >> 3, sc = chunk & 7;
      int gc = (sc ^ (row & 7)) << 3;  // swizzled source chunk (element offset)
      gl16(Ap + (size_t)row * lda + k0 + gc, &lA[chunk * 8]);
      gl16(Wp + (size_t)row * ldw + k0 + gc, &lB[chunk * 8]);
    }
    __syncthreads();
#pragma unroll
    for (int kk = 0; kk < 64; kk += 32) {
      short8 af[4], bfr[4];
#pragma unroll
      for (int i = 0; i < 4; ++i) {
        int ar = wr + i * 16 + lm;
        int ac = (kk >> 3) + lg;
        af[i] = *(const short8*)&lA[ar * 64 + ((ac ^ (ar & 7)) << 3)];
      }
#pragma unroll
      for (int j = 0; j < 4; ++j) {
        int br = wc + j * 16 + lm;
        int bc = (kk >> 3) + lg;
        bfr[j] = *(const short8*)&lB[br * 64 + ((bc ^ (br & 7)) << 3)];
      }
#pragma unroll
      for (int i = 0; i < 4; ++i)
#pragma unroll
        for (int j = 0; j < 4; ++j)
          acc[i][j] = __builtin_amdgcn_mfma_f32_16x16x32_bf16(af[i], bfr[j], acc[i][j], 0, 0, 0);
    }
  }

  // epilogue: D row = (lane>>4)*4 + reg, col = lane&15; optional bias/elu/col-stats
#pragma unroll
  for (int j = 0; j < 4; ++j) {
    int n = nBase + wc + j * 16 + lm;
    float bj = bias ? bias[n] : 0.f;
    float s = 0.f, q = 0.f;
#pragma unroll
    for (int i = 0; i < 4; ++i) {
      int m0 = mBase + wr + i * 16 + lg * 4;
#pragma unroll
      for (int r = 0; r < 4; ++r) {
        float v = acc[i][j][r] + bj;
        if (elu) v = v > 0.f ? v : expm1f(v);
        s += v; q += v * v;
        C[(size_t)(m0 + r) * ldc + n] = f2bf(v);
      }
    }
    if (st) {
      s += __shfl_xor(s, 16, 64); s += __shfl_xor(s, 32, 64);
      q += __shfl_xor(q, 16, 64); q += __shfl_xor(q, 32, 64);
      if (lg == 0) { atomicAdd(&st[n], s); atomicAdd(&st[Ntot + n], q); }
    }
  }
}

// ---------------- fold BN to per-column a*y+b: ab[0..N)=a, ab[N..2N)=b
__global__ void bn_finalize(const float* __restrict__ st, const float* __restrict__ gam,
                            const float* __restrict__ bet, float* __restrict__ ab,
                            int N, float invB) {
  int c = blockIdx.x * blockDim.x + threadIdx.x;
  if (c < N) {
    float m = st[c] * invB;
    float v = st[N + c] * invB - m * m;
    float a = gam[c] * rsqrtf(v + 1e-5f);
    ab[c] = a;
    ab[N + c] = bet[c] - m * a;
  }
}

// ---------------- in-place BN + ELU on bf16 [B,N], 8 elems/thread
__global__ void bn_apply(unsigned short* __restrict__ Y, const float* __restrict__ ab, int N) {
  size_t i = (size_t)blockIdx.x * blockDim.x + threadIdx.x;
  size_t base = i * 8;
  int col = (int)(base % (size_t)N);
  uint4 u = *(uint4*)&Y[base];
  unsigned int uu[4] = {u.x, u.y, u.z, u.w};
  unsigned int oo[4];
#pragma unroll
  for (int k = 0; k < 4; ++k) {
    float vlo = bf2f(uu[k] & 0xFFFFu);
    float vhi = bf2f(uu[k] >> 16);
    int c = col + 2 * k;
    float flo = ab[c] * vlo + ab[N + c];
    float fhi = ab[c + 1] * vhi + ab[N + c + 1];
    flo = flo > 0.f ? flo : expm1f(flo);
    fhi = fhi > 0.f ? fhi : expm1f(fhi);
    oo[k] = (unsigned int)f2bf(flo) | ((unsigned int)f2bf(fhi) << 16);
  }
  uint4 o = {oo[0], oo[1], oo[2], oo[3]};
  *(uint4*)&Y[base] = o;
}

// ---------------- fp32 -> bf16 cast (4/thread)
__global__ void castk(const float* __restrict__ s, unsigned short* __restrict__ d, int n4) {
  int i = blockIdx.x * blockDim.x + threadIdx.x;
  if (i < n4) {
    float4 v = ((const float4*)s)[i];
    ushort4 o = {f2bf(v.x), f2bf(v.y), f2bf(v.z), f2bf(v.w)};
    ((ushort4*)d)[i] = o;
  }
}

// ---------------- cast x [B,512] fp32 into z[:,128:640] bf16 (ld 640)
__global__ void cast_x(const float* __restrict__ x, unsigned short* __restrict__ z) {
  int i = blockIdx.x * blockDim.x + threadIdx.x;  // over B*128
  int b = i >> 7;
  int c = (i & 127) << 2;
  float4 v = *(const float4*)&x[(size_t)b * 512 + c];
  ushort4 o = {f2bf(v.x), f2bf(v.y), f2bf(v.z), f2bf(v.w)};
  *(ushort4*)&z[(size_t)b * 640 + 128 + c] = o;
}

// ---------------- final: select expert, dot(t2[e,b,:], w3[e,:]) + b3[e], softplus
__global__ void final_pred(const unsigned short* __restrict__ t2, const int* __restrict__ gidx,
                           const float* __restrict__ w3, const float* __restrict__ b3,
                           float* __restrict__ out) {
  int row = blockIdx.x * 4 + (threadIdx.x >> 6);
  int l = threadIdx.x & 63;
  int e = gidx[row];
  const unsigned short* p = t2 + ((size_t)e * B_ + row) * 256 + l * 4;
  ushort4 u = *(const ushort4*)p;
  float4 wv = *(const float4*)&w3[e * 256 + l * 4];
  float sum = bf2f(u.x) * wv.x + bf2f(u.y) * wv.y + bf2f(u.z) * wv.z + bf2f(u.w) * wv.w;
#pragma unroll
  for (int off = 32; off; off >>= 1) sum += __shfl_down(sum, off, 64);
  if (l == 0) {
    float xr = sum + b3[e];
    float sp = (xr > 0.f) ? (xr + log1pf(expf(-xr))) : log1pf(expf(xr));
    float pl = -sp;
    out[row] = pl;
    out[B_ + row] = expf(pl * LN10_);
  }
}

extern "C" void kernel_launch(void* const* d_in, const int* in_sizes, int n_in,
                              void* d_out, int out_size, void* d_ws, size_t ws_size,
                              hipStream_t stream) {
  const float* x    = (const float*)d_in[0];
  const int*   gidx = (const int*)d_in[1];
  const float* e_w1 = (const float*)d_in[2];
  const float* e_g1 = (const float*)d_in[4];
  const float* e_be1= (const float*)d_in[5];
  const float* e_w2 = (const float*)d_in[6];
  const float* e_g2 = (const float*)d_in[8];
  const float* e_be2= (const float*)d_in[9];
  const float* e_w3 = (const float*)d_in[10];
  const float* e_b3 = (const float*)d_in[11];
  const float* s_w1 = (const float*)d_in[12];
  const float* s_g1 = (const float*)d_in[14];
  const float* s_be1= (const float*)d_in[15];
  const float* s_w2 = (const float*)d_in[16];
  const float* s_g2 = (const float*)d_in[18];
  const float* s_be2= (const float*)d_in[19];
  const float* h_w1 = (const float*)d_in[20];
  const float* h_b1 = (const float*)d_in[21];
  const float* h_w2 = (const float*)d_in[22];
  const float* h_b2 = (const float*)d_in[23];
  const float* h_w3 = (const float*)d_in[24];
  const float* h_b3 = (const float*)d_in[25];
  float* out = (float*)d_out;

  char* ws = (char*)d_ws;
  size_t off = 0;
  auto alloc = [&](size_t bytes) -> char* {
    char* p = ws + off;
    off += (bytes + 255) & ~(size_t)255;
    return p;
  };
  unsigned short* wb_e1 = (unsigned short*)alloc((size_t)2048 * 512 * 2);
  unsigned short* wb_e2 = (unsigned short*)alloc((size_t)1024 * 2048 * 2);
  unsigned short* wb_e3 = (unsigned short*)alloc((size_t)128 * 1024 * 2);
  unsigned short* wb_s1 = (unsigned short*)alloc((size_t)2048 * 640 * 2);
  unsigned short* wb_s2 = (unsigned short*)alloc((size_t)1024 * 2048 * 2);
  unsigned short* wb_h1 = (unsigned short*)alloc((size_t)3 * 512 * 1024 * 2);
  unsigned short* wb_h2 = (unsigned short*)alloc((size_t)3 * 256 * 512 * 2);
  unsigned short* z     = (unsigned short*)alloc((size_t)B_ * 640 * 2);
  unsigned short* bufA  = (unsigned short*)alloc((size_t)B_ * 2048 * 2);
  unsigned short* bufB  = (unsigned short*)alloc((size_t)B_ * 1024 * 2);
  float* st = (float*)alloc(2 * 2048 * sizeof(float));
  float* ab = (float*)alloc(2 * 2048 * sizeof(float));

  auto cast = [&](const float* s, unsigned short* d, size_t n) {
    int n4 = (int)(n / 4);
    castk<<<(n4 + 255) / 256, 256, 0, stream>>>(s, d, n4);
  };
  cast(e_w1, wb_e1, (size_t)2048 * 512);
  cast(e_w2, wb_e2, (size_t)1024 * 2048);
  cast(e_w3, wb_e3, (size_t)128 * 1024);
  cast(s_w1, wb_s1, (size_t)2048 * 640);
  cast(s_w2, wb_s2, (size_t)1024 * 2048);
  cast(h_w1, wb_h1, (size_t)3 * 512 * 1024);
  cast(h_w2, wb_h2, (size_t)3 * 256 * 512);
  cast_x<<<(B_ * 128) / 256, 256, 0, stream>>>(x, z);

  auto bn_post = [&](unsigned short* Y, int N, const float* g, const float* be) {
    bn_finalize<<<(N + 255) / 256, 256, 0, stream>>>(st, g, be, ab, N, 1.0f / B_);
    bn_apply<<<(int)((size_t)B_ * N / 2048), 256, 0, stream>>>(Y, ab, N);
  };

  // encoder L1: [B,512] x [2048,512]^T -> bufA  (BN stats fused)
  hipMemsetAsync(st, 0, (size_t)2 * 2048 * sizeof(float), stream);
  gemm_bt<<<dim3(16, 256), 256, 0, stream>>>(z + 128, 640, wb_e1, 512, bufA, 2048, 512,
                                             nullptr, 0, st, 2048, 0, 0, 0, 0);
  bn_post(bufA, 2048, e_g1, e_be1);
  // encoder L2: [B,2048] x [1024,2048]^T -> bufB
  hipMemsetAsync(st, 0, (size_t)2 * 1024 * sizeof(float), stream);
  gemm_bt<<<dim3(8, 256), 256, 0, stream>>>(bufA, 2048, wb_e2, 2048, bufB, 1024, 2048,
                                            nullptr, 0, st, 1024, 0, 0, 0, 0);
  bn_post(bufB, 1024, e_g2, e_be2);
  // latent: [B,1024] x [128,1024]^T -> z[:,0:128] (ldc 640), +e_b3
  gemm_bt<<<dim3(1, 256), 256, 0, stream>>>(bufB, 1024, wb_e3, 1024, z, 640, 1024,
                                            e_b3, 0, nullptr, 0, 0, 0, 0, 0);
  // shared L1: [B,640] x [2048,640]^T -> bufA
  hipMemsetAsync(st, 0, (size_t)2 * 2048 * sizeof(float), stream);
  gemm_bt<<<dim3(16, 256), 256, 0, stream>>>(z, 640, wb_s1, 640, bufA, 2048, 640,
                                             nullptr, 0, st, 2048, 0, 0, 0, 0);
  bn_post(bufA, 2048, s_g1, s_be1);
  // shared L2: [B,2048] x [1024,2048]^T -> bufB (= hidden)
  hipMemsetAsync(st, 0, (size_t)2 * 1024 * sizeof(float), stream);
  gemm_bt<<<dim3(8, 256), 256, 0, stream>>>(bufA, 2048, wb_s2, 2048, bufB, 1024, 2048,
                                            nullptr, 0, st, 1024, 0, 0, 0, 0);
  bn_post(bufB, 1024, s_g2, s_be2);

  // heads batched over blockIdx.z: t1 = elu(hidden @ h_w1[e]^T + h_b1[e]) -> bufA slices
  // A is the SHARED hidden -> eA = 0
  gemm_bt<<<dim3(4, 256, 3), 256, 0, stream>>>(bufB, 1024, wb_h1, 1024, bufA, 512, 1024,
                                               h_b1, 1, nullptr, 0,
                                               0L, (long)512 * 1024, (long)B_ * 512, 512);
  // t2 = elu(t1_e @ h_w2[e]^T + h_b2[e]) -> bufB slices; A is PER-EXPERT t1 -> eA = B*512
  gemm_bt<<<dim3(2, 256, 3), 256, 0, stream>>>(bufA, 512, wb_h2, 512, bufB, 256, 512,
                                               h_b2, 1, nullptr, 0,
                                               (long)B_ * 512, (long)256 * 512, (long)B_ * 256, 256);

  final_pred<<<B_ / 4, 256, 0, stream>>>(bufB, gidx, h_w3, h_b3, out);
}

// Round 5
// 1220.284 us; speedup vs baseline: 1.3829x; 1.0281x over previous
//
#include <hip/hip_runtime.h>
#include <math.h>

#define B_    32768
#define LN10_ 2.302585092994046f

typedef __attribute__((ext_vector_type(8))) short short8;
typedef __attribute__((ext_vector_type(4))) float f32x4;

typedef const __attribute__((address_space(1))) void gvoid_t;
typedef __attribute__((address_space(3))) void svoid_t;

__device__ __forceinline__ void gl16(const void* g, void* l) {
  __builtin_amdgcn_global_load_lds((gvoid_t*)g, (svoid_t*)l, 16, 0, 0);
}

__device__ __forceinline__ float bf2f(unsigned int u) {
  union { unsigned int i; float f; } v; v.i = u << 16; return v.f;
}
// round-to-nearest-even f32 -> bf16 (finite inputs)
__device__ __forceinline__ unsigned short f2bf(float f) {
  union { float f; unsigned int i; } v; v.f = f;
  unsigned int x = v.i;
  unsigned int r = x + 0x7FFFu + ((x >> 16) & 1u);
  return (unsigned short)(r >> 16);
}

// ---------------- GEMM: C[m,n] = sum_k A[m,k] * W[n,k]  (+bias, +elu, +col-stats)
// bf16 in/out, fp32 acc. grid: (N/128, M/128, E), block 256. Tile 128x128x64.
// LDS XOR swizzle (R4: SQ_LDS_BANK_CONFLICT 5e7 -> 0).
// XCD block swizzle (R4: big-GEMM FETCH 532 -> 131 MB ~= ideal).
// Batched experts via blockIdx.z strides; eA is in ELEMENTS (column offset ok).
__global__ __launch_bounds__(256)
void gemm_bt(const unsigned short* __restrict__ A0, int lda,
             const unsigned short* __restrict__ W0, int ldw,
             unsigned short* __restrict__ C0, int ldc,
             int K, const float* __restrict__ bias0, int elu,
             float* __restrict__ st, int Ntot,
             long eA, long eW, long eC, int eBias) {
  __shared__ __align__(16) unsigned short lA[128 * 64];
  __shared__ __align__(16) unsigned short lB[128 * 64];
  const int t = threadIdx.x;
  const int nx = gridDim.x, ny = gridDim.y;
  const int f = blockIdx.y * nx + blockIdx.x;
  const int xcd = f & 7, g = f >> 3;
  const int gdiv = g / nx;
  const int mt = xcd * (ny >> 3) + gdiv;
  const int nt = g - gdiv * nx;
  const int mBase = mt * 128;
  const int nBase = nt * 128;
  const unsigned short* A = A0 + (size_t)blockIdx.z * eA;
  const unsigned short* W = W0 + (size_t)blockIdx.z * eW;
  unsigned short* C = C0 + (size_t)blockIdx.z * eC;
  const float* bias = bias0 ? (bias0 + (size_t)blockIdx.z * eBias) : nullptr;
  const unsigned short* Ap = A + (size_t)mBase * lda;
  const unsigned short* Wp = W + (size_t)nBase * ldw;
  const int w = t >> 6, l = t & 63;
  const int wr = (w >> 1) * 64, wc = (w & 1) * 64;
  const int lm = l & 15, lg = l >> 4;

  f32x4 acc[4][4];
#pragma unroll
  for (int i = 0; i < 4; ++i)
#pragma unroll
    for (int j = 0; j < 4; ++j) {
      f32x4 z4 = {0.f, 0.f, 0.f, 0.f};
      acc[i][j] = z4;
    }

  for (int k0 = 0; k0 < K; k0 += 64) {
    __syncthreads();
#pragma unroll
    for (int it = 0; it < 4; ++it) {
      int chunk = it * 256 + t;
      int row = chunk >> 3, sc = chunk & 7;
      int gc = (sc ^ (row & 7)) << 3;  // swizzled source chunk (element offset)
      gl16(Ap + (size_t)row * lda + k0 + gc, &lA[chunk * 8]);
      gl16(Wp + (size_t)row * ldw + k0 + gc, &lB[chunk * 8]);
    }
    __syncthreads();
#pragma unroll
    for (int kk = 0; kk < 64; kk += 32) {
      short8 af[4], bfr[4];
#pragma unroll
      for (int i = 0; i < 4; ++i) {
        int ar = wr + i * 16 + lm;
        int ac = (kk >> 3) + lg;
        af[i] = *(const short8*)&lA[ar * 64 + ((ac ^ (ar & 7)) << 3)];
      }
#pragma unroll
      for (int j = 0; j < 4; ++j) {
        int br = wc + j * 16 + lm;
        int bc = (kk >> 3) + lg;
        bfr[j] = *(const short8*)&lB[br * 64 + ((bc ^ (br & 7)) << 3)];
      }
#pragma unroll
      for (int i = 0; i < 4; ++i)
#pragma unroll
        for (int j = 0; j < 4; ++j)
          acc[i][j] = __builtin_amdgcn_mfma_f32_16x16x32_bf16(af[i], bfr[j], acc[i][j], 0, 0, 0);
    }
  }

  // epilogue: D row = (lane>>4)*4 + reg, col = lane&15; optional bias/elu/col-stats
#pragma unroll
  for (int j = 0; j < 4; ++j) {
    int n = nBase + wc + j * 16 + lm;
    float bj = bias ? bias[n] : 0.f;
    float s = 0.f, q = 0.f;
#pragma unroll
    for (int i = 0; i < 4; ++i) {
      int m0 = mBase + wr + i * 16 + lg * 4;
#pragma unroll
      for (int r = 0; r < 4; ++r) {
        float v = acc[i][j][r] + bj;
        if (elu) v = v > 0.f ? v : expm1f(v);
        s += v; q += v * v;
        C[(size_t)(m0 + r) * ldc + n] = f2bf(v);
      }
    }
    if (st) {
      s += __shfl_xor(s, 16, 64); s += __shfl_xor(s, 32, 64);
      q += __shfl_xor(q, 16, 64); q += __shfl_xor(q, 32, 64);
      if (lg == 0) { atomicAdd(&st[n], s); atomicAdd(&st[Ntot + n], q); }
    }
  }
}

// ---------------- in-place BN + ELU on bf16 [B,N], 8 elems/thread.
// a/b computed inline from st/gamma/beta (redundant VALU is free; kernel is
// memory-bound and st/gamma/beta are L2-resident broadcasts). N must be pow2.
__global__ void bn_apply(unsigned short* __restrict__ Y, const float* __restrict__ st,
                         const float* __restrict__ gam, const float* __restrict__ bet,
                         int N, float invB) {
  size_t i = (size_t)blockIdx.x * blockDim.x + threadIdx.x;
  size_t base = i * 8;
  int col = (int)(base & (size_t)(N - 1));
  float a8[8], b8[8];
#pragma unroll
  for (int k = 0; k < 8; ++k) {
    int c = col + k;
    float m = st[c] * invB;
    float var = st[N + c] * invB - m * m;
    float av = gam[c] * rsqrtf(var + 1e-5f);
    a8[k] = av;
    b8[k] = bet[c] - m * av;
  }
  uint4 u = *(uint4*)&Y[base];
  unsigned int uu[4] = {u.x, u.y, u.z, u.w};
  unsigned int oo[4];
#pragma unroll
  for (int k = 0; k < 4; ++k) {
    float vlo = bf2f(uu[k] & 0xFFFFu);
    float vhi = bf2f(uu[k] >> 16);
    float flo = a8[2 * k] * vlo + b8[2 * k];
    float fhi = a8[2 * k + 1] * vhi + b8[2 * k + 1];
    flo = flo > 0.f ? flo : expm1f(flo);
    fhi = fhi > 0.f ? fhi : expm1f(fhi);
    oo[k] = (unsigned int)f2bf(flo) | ((unsigned int)f2bf(fhi) << 16);
  }
  uint4 o = {oo[0], oo[1], oo[2], oo[3]};
  *(uint4*)&Y[base] = o;
}

// ---------------- cast ALL weights fp32->bf16 in one launch.
// Source region table in float4 units (compile-time; weight dims are fixed):
// e1[0,262144) e2[.,786432) e3[.,819200) s1[.,1146880) s2[.,1671168)
// h1[.,2064384) h2[.,2162688). Dest bf16 buffers are contiguous in the same
// order (each region's byte size is a multiple of 256), so dst index == i4.
__global__ void cast_all(const float* __restrict__ e1, const float* __restrict__ e2,
                         const float* __restrict__ e3, const float* __restrict__ s1,
                         const float* __restrict__ s2, const float* __restrict__ h1,
                         const float* __restrict__ h2, unsigned short* __restrict__ dst) {
  int i4 = blockIdx.x * 256 + threadIdx.x;
  const float* src;
  int rel;
  if (i4 < 786432) {
    if (i4 < 262144) { src = e1; rel = i4; }
    else             { src = e2; rel = i4 - 262144; }
  } else if (i4 < 1146880) {
    if (i4 < 819200) { src = e3; rel = i4 - 786432; }
    else             { src = s1; rel = i4 - 819200; }
  } else if (i4 < 2064384) {
    if (i4 < 1671168) { src = s2; rel = i4 - 1146880; }
    else              { src = h1; rel = i4 - 1671168; }
  } else { src = h2; rel = i4 - 2064384; }
  float4 v = ((const float4*)src)[rel];
  ushort4 o = {f2bf(v.x), f2bf(v.y), f2bf(v.z), f2bf(v.w)};
  ((ushort4*)dst)[i4] = o;
}

// ---------------- cast x [B,512] fp32 into z[:,128:640] bf16 (ld 640)
__global__ void cast_x(const float* __restrict__ x, unsigned short* __restrict__ z) {
  int i = blockIdx.x * blockDim.x + threadIdx.x;  // over B*128
  int b = i >> 7;
  int c = (i & 127) << 2;
  float4 v = *(const float4*)&x[(size_t)b * 512 + c];
  ushort4 o = {f2bf(v.x), f2bf(v.y), f2bf(v.z), f2bf(v.w)};
  *(ushort4*)&z[(size_t)b * 640 + 128 + c] = o;
}

// ---------------- final: select expert, dot(t2[b, e*256:(e+1)*256], w3[e,:]) + b3[e]
// t2 layout: [B, 768] interleaved experts (ld 768).
__global__ void final_pred(const unsigned short* __restrict__ t2, const int* __restrict__ gidx,
                           const float* __restrict__ w3, const float* __restrict__ b3,
                           float* __restrict__ out) {
  int row = blockIdx.x * 4 + (threadIdx.x >> 6);
  int l = threadIdx.x & 63;
  int e = gidx[row];
  const unsigned short* p = t2 + (size_t)row * 768 + e * 256 + l * 4;
  ushort4 u = *(const ushort4*)p;
  float4 wv = *(const float4*)&w3[e * 256 + l * 4];
  float sum = bf2f(u.x) * wv.x + bf2f(u.y) * wv.y + bf2f(u.z) * wv.z + bf2f(u.w) * wv.w;
#pragma unroll
  for (int off = 32; off; off >>= 1) sum += __shfl_down(sum, off, 64);
  if (l == 0) {
    float xr = sum + b3[e];
    float sp = (xr > 0.f) ? (xr + log1pf(expf(-xr))) : log1pf(expf(xr));
    float pl = -sp;
    out[row] = pl;
    out[B_ + row] = expf(pl * LN10_);
  }
}

extern "C" void kernel_launch(void* const* d_in, const int* in_sizes, int n_in,
                              void* d_out, int out_size, void* d_ws, size_t ws_size,
                              hipStream_t stream) {
  const float* x    = (const float*)d_in[0];
  const int*   gidx = (const int*)d_in[1];
  const float* e_w1 = (const float*)d_in[2];
  const float* e_g1 = (const float*)d_in[4];
  const float* e_be1= (const float*)d_in[5];
  const float* e_w2 = (const float*)d_in[6];
  const float* e_g2 = (const float*)d_in[8];
  const float* e_be2= (const float*)d_in[9];
  const float* e_w3 = (const float*)d_in[10];
  const float* e_b3 = (const float*)d_in[11];
  const float* s_w1 = (const float*)d_in[12];
  const float* s_g1 = (const float*)d_in[14];
  const float* s_be1= (const float*)d_in[15];
  const float* s_w2 = (const float*)d_in[16];
  const float* s_g2 = (const float*)d_in[18];
  const float* s_be2= (const float*)d_in[19];
  const float* h_w1 = (const float*)d_in[20];
  const float* h_b1 = (const float*)d_in[21];
  const float* h_w2 = (const float*)d_in[22];
  const float* h_b2 = (const float*)d_in[23];
  const float* h_w3 = (const float*)d_in[24];
  const float* h_b3 = (const float*)d_in[25];
  float* out = (float*)d_out;

  char* ws = (char*)d_ws;
  size_t off = 0;
  auto alloc = [&](size_t bytes) -> char* {
    char* p = ws + off;
    off += (bytes + 255) & ~(size_t)255;
    return p;
  };
  // bf16 weight buffers MUST stay contiguous & in this order (cast_all table)
  unsigned short* wb_e1 = (unsigned short*)alloc((size_t)2048 * 512 * 2);
  unsigned short* wb_e2 = (unsigned short*)alloc((size_t)1024 * 2048 * 2);
  unsigned short* wb_e3 = (unsigned short*)alloc((size_t)128 * 1024 * 2);
  unsigned short* wb_s1 = (unsigned short*)alloc((size_t)2048 * 640 * 2);
  unsigned short* wb_s2 = (unsigned short*)alloc((size_t)1024 * 2048 * 2);
  unsigned short* wb_h1 = (unsigned short*)alloc((size_t)3 * 512 * 1024 * 2);
  unsigned short* wb_h2 = (unsigned short*)alloc((size_t)3 * 256 * 512 * 2);
  unsigned short* z     = (unsigned short*)alloc((size_t)B_ * 640 * 2);
  unsigned short* bufA  = (unsigned short*)alloc((size_t)B_ * 2048 * 2);
  unsigned short* bufB  = (unsigned short*)alloc((size_t)B_ * 1024 * 2);
  float* st = (float*)alloc(12288 * sizeof(float));  // 4 regions
  float* st0 = st;            // e1: 2*2048
  float* st1 = st + 4096;     // e2: 2*1024
  float* st2 = st + 6144;     // s1: 2*2048
  float* st3 = st + 10240;    // s2: 2*1024

  cast_all<<<8448, 256, 0, stream>>>(e_w1, e_w2, e_w3, s_w1, s_w2, h_w1, h_w2, wb_e1);
  cast_x<<<(B_ * 128) / 256, 256, 0, stream>>>(x, z);
  hipMemsetAsync(st, 0, 12288 * sizeof(float), stream);

  // encoder L1: [B,512] x [2048,512]^T -> bufA  (BN stats fused)
  gemm_bt<<<dim3(16, 256), 256, 0, stream>>>(z + 128, 640, wb_e1, 512, bufA, 2048, 512,
                                             nullptr, 0, st0, 2048, 0, 0, 0, 0);
  bn_apply<<<(int)((size_t)B_ * 2048 / 2048), 256, 0, stream>>>(bufA, st0, e_g1, e_be1, 2048, 1.0f / B_);
  // encoder L2: [B,2048] x [1024,2048]^T -> bufB
  gemm_bt<<<dim3(8, 256), 256, 0, stream>>>(bufA, 2048, wb_e2, 2048, bufB, 1024, 2048,
                                            nullptr, 0, st1, 1024, 0, 0, 0, 0);
  bn_apply<<<(int)((size_t)B_ * 1024 / 2048), 256, 0, stream>>>(bufB, st1, e_g2, e_be2, 1024, 1.0f / B_);
  // latent: [B,1024] x [128,1024]^T -> z[:,0:128] (ldc 640), +e_b3
  gemm_bt<<<dim3(1, 256), 256, 0, stream>>>(bufB, 1024, wb_e3, 1024, z, 640, 1024,
                                            e_b3, 0, nullptr, 0, 0, 0, 0, 0);
  // shared L1: [B,640] x [2048,640]^T -> bufA
  gemm_bt<<<dim3(16, 256), 256, 0, stream>>>(z, 640, wb_s1, 640, bufA, 2048, 640,
                                             nullptr, 0, st2, 2048, 0, 0, 0, 0);
  bn_apply<<<(int)((size_t)B_ * 2048 / 2048), 256, 0, stream>>>(bufA, st2, s_g1, s_be1, 2048, 1.0f / B_);
  // shared L2: [B,2048] x [1024,2048]^T -> bufB (= hidden)
  gemm_bt<<<dim3(8, 256), 256, 0, stream>>>(bufA, 2048, wb_s2, 2048, bufB, 1024, 2048,
                                            nullptr, 0, st3, 1024, 0, 0, 0, 0);
  bn_apply<<<(int)((size_t)B_ * 1024 / 2048), 256, 0, stream>>>(bufB, st3, s_g2, s_be2, 1024, 1.0f / B_);

  // head L1 as ONE GEMM: wb_h1's [3,512,1024] layout IS [1536,1024]; h_b1 IS [1536].
  // t1 = elu(hidden @ Wh1^T + bh1) -> bufA as [B,1536] (ldc 1536)
  gemm_bt<<<dim3(12, 256), 256, 0, stream>>>(bufB, 1024, wb_h1, 1024, bufA, 1536, 1024,
                                             h_b1, 1, nullptr, 0, 0, 0, 0, 0);
  // head L2 z-batched: A = t1[:, e*512:(e+1)*512] (eA=512 elements, lda=1536),
  // C = t2[:, e*256:(e+1)*256] (eC=256, ldc=768) -> bufB (hidden dead)
  gemm_bt<<<dim3(2, 256, 3), 256, 0, stream>>>(bufA, 1536, wb_h2, 512, bufB, 768, 512,
                                               h_b2, 1, nullptr, 0,
                                               512L, (long)256 * 512, 256L, 256);

  final_pred<<<B_ / 4, 256, 0, stream>>>(bufB, gidx, h_w3, h_b3, out);
}